// Round 7
// baseline (93.242 us; speedup 1.0000x reference)
//
#include <hip/hip_runtime.h>
#include <math.h>

#define NB 2
#define SS 256
#define DD 768
#define NH 12
#define WW 64

using f32x2  = __attribute__((ext_vector_type(2))) float;
using f32x4  = __attribute__((ext_vector_type(4))) float;
using bf16x8 = __attribute__((ext_vector_type(8))) short;

constexpr float R2    = 0.25f;           // R/2: revolutions pre-scale for v_sin/v_cos
constexpr float C8    = 4.1168160e-7f;   // (2*pi)^-8
constexpr float EPS   = 1e-4f;
constexpr float SNEPS = 6.2831853e-4f;   // 2*pi*EPS: guarded dim contributes exactly 1

// ws layout (bytes):
//   qkv f32:  [0, 4718592)         3 * (2*12*256*64) * 4
//   A' bf16:  [4718592, 6291456)   512 x 1536  (xh | xl)
//   B' bf16:  [6291456, 13369344)  2304 x 1536 (Wh | Wl)
//   QT2 f32:  [13369344, 18087936) [bh][pair(128)][type(3)][dim(64)][2]  (q*R2,sin,cos) row-pairs
//   KT  f32:  [18087936, 22806528) [bh][dim][3][256] key-coalesced
#define QKV_ELEMS (NB*NH*SS*WW)
#define A_OFF_BYTES  4718592u
#define B_OFF_BYTES  6291456u
#define QT_OFF_BYTES 13369344u
#define KT_OFF_BYTES 18087936u

#define XBLKS 384    // 512*768/4/256
#define WBLKS 1728   // 3*768*768/4/256

__device__ __forceinline__ unsigned short bf16_rn(float f) {
    unsigned u = __builtin_bit_cast(unsigned, f);
    u += 0x7fffu + ((u >> 16) & 1u);
    return (unsigned short)(u >> 16);
}

// ---------------- merged split conversions: x -> A' [xh|xl], W -> B' [Wh|Wl] ----------------
__global__ __launch_bounds__(256) void conv_all(
        const float* __restrict__ x,
        const float* __restrict__ Wq, const float* __restrict__ Wk, const float* __restrict__ Wv,
        unsigned short* __restrict__ A, unsigned short* __restrict__ B) {
    int bid = blockIdx.x;
    const float* src;
    unsigned short* dstrow;
    if (bid < XBLKS) {
        int idx = bid * 256 + threadIdx.x;
        int m = idx / (DD/4);
        int c = (idx - m*(DD/4)) * 4;
        src = x + (size_t)idx * 4;
        dstrow = A + (size_t)m * 1536 + c;
    } else {
        int idx = (bid - XBLKS) * 256 + threadIdx.x;
        int p = idx / (768*192);
        int rem = idx - p*(768*192);
        const float* W = (p == 0) ? Wq : (p == 1) ? Wk : Wv;
        int j = rem / 192;
        int c = (rem - j*192) * 4;
        src = W + (size_t)rem * 4;
        dstrow = B + (size_t)(p*768 + j) * 1536 + c;
    }
    float4 v = *reinterpret_cast<const float4*>(src);
    float vv[4] = {v.x, v.y, v.z, v.w};
    unsigned short h[4], l[4];
    #pragma unroll
    for (int e = 0; e < 4; ++e) {
        h[e] = bf16_rn(vv[e]);
        float hf = __builtin_bit_cast(float, (unsigned)h[e] << 16);
        l[e] = bf16_rn(vv[e] - hf);
    }
    *reinterpret_cast<ushort4*>(dstrow)       = make_ushort4(h[0], h[1], h[2], h[3]);
    *reinterpret_cast<ushort4*>(dstrow + 768) = make_ushort4(l[0], l[1], l[2], l[3]);
}

// ---------------- split-bf16 MFMA GEMM (unchanged from R6) ----------------
__global__ __launch_bounds__(256, 2) void gemm_qkv(
        const unsigned short* __restrict__ A, const unsigned short* __restrict__ B,
        const float* __restrict__ bq, const float* __restrict__ bk, const float* __restrict__ bv,
        float* __restrict__ qkv) {
    __shared__ float red[4][32*32];
    const int tid = threadIdx.x;
    const int wid = tid >> 6, l = tid & 63;
    const int lr = l & 15, lo_ = l >> 4;
    const int m0 = blockIdx.x * 32, n0 = blockIdx.y * 32;

    const unsigned short* Ap = A + (size_t)(m0 + lr) * 1536 + wid * 192 + lo_ * 8;
    const unsigned short* Bp = B + (size_t)(n0 + lr) * 1536 + wid * 192 + lo_ * 8;

    f32x4 acc00 = 0.f, acc01 = 0.f, acc10 = 0.f, acc11 = 0.f;

    bf16x8 ca0, ca1, cb0, cb1, na0, na1, nb0, nb1;
    ca0 = *reinterpret_cast<const bf16x8*>(Ap);
    ca1 = *reinterpret_cast<const bf16x8*>(Ap + 16*1536);
    cb0 = *reinterpret_cast<const bf16x8*>(Bp);
    cb1 = *reinterpret_cast<const bf16x8*>(Bp + 16*1536);

    #pragma unroll
    for (int it = 0; it < 18; ++it) {
        if (it < 17) {
            const int it1 = it + 1;
            const int seg1 = it1 / 6, kk1 = it1 - seg1 * 6;
            const int ao = ((seg1 == 2) ? 768 : 0) + kk1 * 32;
            const int bo = ((seg1 == 1) ? 768 : 0) + kk1 * 32;
            na0 = *reinterpret_cast<const bf16x8*>(Ap + ao);
            na1 = *reinterpret_cast<const bf16x8*>(Ap + 16*1536 + ao);
            nb0 = *reinterpret_cast<const bf16x8*>(Bp + bo);
            nb1 = *reinterpret_cast<const bf16x8*>(Bp + 16*1536 + bo);
        }
        acc00 = __builtin_amdgcn_mfma_f32_16x16x32_bf16(ca0, cb0, acc00, 0, 0, 0);
        acc01 = __builtin_amdgcn_mfma_f32_16x16x32_bf16(ca0, cb1, acc01, 0, 0, 0);
        acc10 = __builtin_amdgcn_mfma_f32_16x16x32_bf16(ca1, cb0, acc10, 0, 0, 0);
        acc11 = __builtin_amdgcn_mfma_f32_16x16x32_bf16(ca1, cb1, acc11, 0, 0, 0);
        ca0 = na0; ca1 = na1; cb0 = nb0; cb1 = nb1;
    }

    #pragma unroll
    for (int j = 0; j < 4; ++j) {
        int r0 = lo_ * 4 + j;
        red[wid][(r0     ) * 32 + lr     ] = acc00[j];
        red[wid][(r0     ) * 32 + lr + 16] = acc01[j];
        red[wid][(r0 + 16) * 32 + lr     ] = acc10[j];
        red[wid][(r0 + 16) * 32 + lr + 16] = acc11[j];
    }
    __syncthreads();

    int row = tid >> 3, col = (tid & 7) * 4;
    f32x4 s = *reinterpret_cast<f32x4*>(&red[0][row*32 + col]);
    #pragma unroll
    for (int w = 1; w < 4; ++w)
        s += *reinterpret_cast<f32x4*>(&red[w][row*32 + col]);

    int n = n0 + col;
    int which = n / 768;
    int jj = n - which * 768;
    const float* bias = (which == 0) ? bq : (which == 1) ? bk : bv;
    float4 bb = *reinterpret_cast<const float4*>(&bias[jj]);
    s[0] += bb.x; s[1] += bb.y; s[2] += bb.z; s[3] += bb.w;

    int m = m0 + row, b_ = m >> 8, s_ = m & 255;
    int head = jj >> 6, w = jj & 63;
    float* o = qkv + (size_t)which * QKV_ELEMS + (((size_t)b_ * NH + head) * SS + s_) * WW + w;
    *reinterpret_cast<float4*>(o) = make_float4(s[0], s[1], s[2], s[3]);
}

// ---------------- prep: q,k -> (val*R2, sin, cos); q in row-pair layout, k key-coalesced ----------------
__global__ __launch_bounds__(256) void prep(const float* __restrict__ qkv,
                                            float* __restrict__ QT, float* __restrict__ KT) {
    const int c = blockIdx.x, bh = blockIdx.y;
    const int lane = threadIdx.x & 63, wv = threadIdx.x >> 6;
    const int key = c * 64 + lane;
    const int d0 = wv * 16;
    const float* q = qkv + ((size_t)bh * SS + key) * WW + d0;
    const float* k = qkv + QKV_ELEMS + ((size_t)bh * SS + key) * WW + d0;
    // QT2: [bh][pair][ty][d][half] floats; per pair-block 384 floats
    float* qt = QT + ((size_t)bh * 128 + (key >> 1)) * 384 + (key & 1);
    float* kt = KT + (size_t)bh * WW * 3 * SS;
    #pragma unroll
    for (int g = 0; g < 4; ++g) {
        float4 qv = *reinterpret_cast<const float4*>(q + g * 4);
        float4 kv = *reinterpret_cast<const float4*>(k + g * 4);
        float qa[4] = {qv.x, qv.y, qv.z, qv.w};
        float ka[4] = {kv.x, kv.y, kv.z, kv.w};
        #pragma unroll
        for (int e = 0; e < 4; ++e) {
            int d = d0 + g * 4 + e;
            float aq = R2 * qa[e];
            qt[0*128 + d*2] = aq;
            qt[1*128 + d*2] = __builtin_amdgcn_sinf(aq);
            qt[2*128 + d*2] = __builtin_amdgcn_cosf(aq);
            float ak = R2 * ka[e];
            kt[(d*3 + 0)*SS + key] = ak;
            kt[(d*3 + 1)*SS + key] = __builtin_amdgcn_sinf(ak);
            kt[(d*3 + 2)*SS + key] = __builtin_amdgcn_cosf(ak);
        }
    }
}

__device__ __forceinline__ void loadk(const float* __restrict__ kg,
                                      float* kk, float* sk, float* ck) {
    #pragma unroll
    for (int j = 0; j < 8; ++j) {
        kk[j] = kg[j*3*SS];
        sk[j] = kg[j*3*SS + SS];
        ck[j] = kg[j*3*SS + 2*SS];
    }
}

// ---------------- Fourier attention v6: pk-packed row-pairs, SGPR q, early-out ----------------
// thread = key. No LDS in the score loop: q triples via uniform (scalar) loads,
// k triples per-lane global loads (double-buffered across groups), math in f32x2
// over row pairs (v_pk_*). |pg| monotonically shrinks; after 3 of 8 groups, if the
// whole wave is below 2^-7 every score rounds to exp()->1.0f exactly -> skip rest.
__global__ __launch_bounds__(256, 3) void fattn(
    const float* __restrict__ qkv, const float* __restrict__ QT, const float* __restrict__ KT,
    const float* __restrict__ mask, float* __restrict__ out)
{
    const int bh = blockIdx.y;
    const int b = bh / NH, h = bh - b * NH;
    const int row0 = blockIdx.x * 8;

    const float* Vg = qkv + (size_t)(2 * QKV_ELEMS) + (size_t)bh * SS * WW;
    const float* kt = KT + (size_t)bh * WW * 3 * SS;

    __shared__ __align__(16) float ebuf[SS][8];      // 8 KB
    __shared__ __align__(16) float ypart[4][8][WW];  // 8 KB
    __shared__ float zs[4][8];

    const int tid = threadIdx.x, lane = tid & 63, wid = tid >> 6;
    const float mt = -10000.0f * (1.0f - mask[b * SS + tid]);

    // uniform q-pair base pointers (f32x2 units; 192 per pair-block)
    const f32x2* qpr[4];
    #pragma unroll
    for (int p = 0; p < 4; ++p)
        qpr[p] = (const f32x2*)QT + ((size_t)bh * 128 + (row0 >> 1) + p) * 192;

    float ka[2][8], sa[2][8], ca[2][8];
    loadk(kt + tid, ka[0], sa[0], ca[0]);

    f32x2 pg0 = {1.f,1.f}, pg1 = {1.f,1.f}, pg2 = {1.f,1.f}, pg3 = {1.f,1.f};
    const f32x2 EPS2 = {EPS, EPS};

    int glim = 8;
    #pragma unroll 2
    for (int g = 0; g < glim; ++g) {
        const int P = g & 1;
        if (g < 7) loadk(kt + (size_t)(g + 1) * 24 * SS + tid, ka[P^1], sa[P^1], ca[P^1]);
        // splat k triples once per group (reused by all 4 pairs)
        f32x2 k2[8], s2[8], c2[8];
        #pragma unroll
        for (int j = 0; j < 8; ++j) {
            k2[j][0] = ka[P][j]; k2[j][1] = ka[P][j];
            s2[j][0] = sa[P][j]; s2[j][1] = sa[P][j];
            c2[j][0] = ca[P][j]; c2[j][1] = ca[P][j];
        }
        #pragma unroll
        for (int p = 0; p < 4; ++p) {
            const f32x2* qv = qpr[p]       + g * 8;
            const f32x2* qs = qpr[p] + 64  + g * 8;
            const f32x2* qc = qpr[p] + 128 + g * 8;
            f32x2 ps = {1.f,1.f}, pt = {1.f,1.f};
            #pragma unroll
            for (int j = 0; j < 8; ++j) {
                f32x2 t   = qv[j] - k2[j];
                f32x2 at  = __builtin_elementwise_max(t, -t);
                f32x2 atc = __builtin_elementwise_max(at, EPS2);
                f32x2 sn  = __builtin_elementwise_fma(qs[j], c2[j], -(qc[j] * s2[j]));
                sn[0] = (at[0] < EPS) ? SNEPS : sn[0];
                sn[1] = (at[1] < EPS) ? SNEPS : sn[1];
                ps *= sn;
                pt *= atc;
            }
            f32x2 f;
            f[0] = (ps[0] * C8) * __builtin_amdgcn_rcpf(pt[0]);
            f[1] = (ps[1] * C8) * __builtin_amdgcn_rcpf(pt[1]);
            if      (p == 0) pg0 *= f;
            else if (p == 1) pg1 *= f;
            else if (p == 2) pg2 *= f;
            else             pg3 *= f;
        }
        if (g == 2) {
            f32x2 m = __builtin_elementwise_max(pg0, -pg0);
            m = __builtin_elementwise_max(m, __builtin_elementwise_max(pg1, -pg1));
            m = __builtin_elementwise_max(m, __builtin_elementwise_max(pg2, -pg2));
            m = __builtin_elementwise_max(m, __builtin_elementwise_max(pg3, -pg3));
            if (!__any(fmaxf(m[0], m[1]) > 0.0078125f)) glim = 3;   // all scores round to exp->1
        }
    }

    // score = pg^4; e = exp(score + maskterm)
    pg0 *= pg0; pg0 *= pg0;
    pg1 *= pg1; pg1 *= pg1;
    pg2 *= pg2; pg2 *= pg2;
    pg3 *= pg3; pg3 *= pg3;
    float e[8];
    e[0] = __expf(pg0[0] + mt); e[1] = __expf(pg0[1] + mt);
    e[2] = __expf(pg1[0] + mt); e[3] = __expf(pg1[1] + mt);
    e[4] = __expf(pg2[0] + mt); e[5] = __expf(pg2[1] + mt);
    e[6] = __expf(pg3[0] + mt); e[7] = __expf(pg3[1] + mt);

    {
        f32x4 e0, e1;
        #pragma unroll
        for (int r = 0; r < 4; ++r) { e0[r] = e[r]; e1[r] = e[r+4]; }
        *reinterpret_cast<f32x4*>(&ebuf[tid][0]) = e0;   // wave-local
        *reinterpret_cast<f32x4*>(&ebuf[tid][4]) = e1;
    }
    #pragma unroll
    for (int r = 0; r < 8; ++r) {
        float z = e[r];
        #pragma unroll
        for (int off = 32; off; off >>= 1) z += __shfl_xor(z, off);
        if (lane == 0) zs[wid][r] = z;
    }

    // PV: lane = output dim w; wave covers its own 64 keys
    float y[8] = {0.f,0.f,0.f,0.f,0.f,0.f,0.f,0.f};
    const float* vb = Vg + (size_t)(wid * 64) * WW + lane;
    #pragma unroll 16
    for (int ii = 0; ii < 64; ++ii) {
        float v = vb[ii * WW];
        f32x4 ea = *reinterpret_cast<const f32x4*>(&ebuf[wid*64 + ii][0]);
        f32x4 eb = *reinterpret_cast<const f32x4*>(&ebuf[wid*64 + ii][4]);
        y[0] = fmaf(ea[0], v, y[0]); y[1] = fmaf(ea[1], v, y[1]);
        y[2] = fmaf(ea[2], v, y[2]); y[3] = fmaf(ea[3], v, y[3]);
        y[4] = fmaf(eb[0], v, y[4]); y[5] = fmaf(eb[1], v, y[5]);
        y[6] = fmaf(eb[2], v, y[6]); y[7] = fmaf(eb[3], v, y[7]);
    }
    #pragma unroll
    for (int r = 0; r < 8; ++r) ypart[wid][r][lane] = y[r];
    __syncthreads();

    {
        const int r0 = tid >> 6;
        #pragma unroll
        for (int q = 0; q < 2; ++q) {
            int rr = r0 + q * 4;
            float yy = ypart[0][rr][lane] + ypart[1][rr][lane]
                     + ypart[2][rr][lane] + ypart[3][rr][lane];
            float zz = zs[0][rr] + zs[1][rr] + zs[2][rr] + zs[3][rr];
            out[((size_t)b * SS + row0 + rr) * DD + h * WW + lane] = yy * __builtin_amdgcn_rcpf(zz);
        }
    }
}

extern "C" void kernel_launch(void* const* d_in, const int* in_sizes, int n_in,
                              void* d_out, int out_size, void* d_ws, size_t ws_size,
                              hipStream_t stream) {
    const float* x    = (const float*)d_in[0];
    const float* mask = (const float*)d_in[1];
    const float* Wq   = (const float*)d_in[2];
    const float* bq   = (const float*)d_in[3];
    const float* Wk   = (const float*)d_in[4];
    const float* bk   = (const float*)d_in[5];
    const float* Wv   = (const float*)d_in[6];
    const float* bv   = (const float*)d_in[7];
    float* out = (float*)d_out;

    float*          qkv = (float*)d_ws;
    unsigned short* Ab  = (unsigned short*)((char*)d_ws + A_OFF_BYTES);
    unsigned short* Bb  = (unsigned short*)((char*)d_ws + B_OFF_BYTES);
    float*          QTp = (float*)((char*)d_ws + QT_OFF_BYTES);
    float*          KTp = (float*)((char*)d_ws + KT_OFF_BYTES);

    conv_all<<<dim3(XBLKS + WBLKS), 256, 0, stream>>>(x, Wq, Wk, Wv, Ab, Bb);
    gemm_qkv<<<dim3(512/32, 2304/32), 256, 0, stream>>>(Ab, Bb, bq, bk, bv, qkv);
    prep<<<dim3(4, NB*NH), 256, 0, stream>>>(qkv, QTp, KTp);
    fattn<<<dim3(SS/8, NB*NH), 256, 0, stream>>>(qkv, QTp, KTp, mask, out);
}

// Round 8
// 69.170 us; speedup vs baseline: 1.3480x; 1.3480x over previous
//
#include <hip/hip_runtime.h>
#include <math.h>

#define NB 2
#define SS 256
#define DD 768
#define NH 12
#define WW 64

using f32x4  = __attribute__((ext_vector_type(4))) float;
using bf16x8 = __attribute__((ext_vector_type(8))) short;

constexpr float R2  = 0.25f;           // R/2: revolutions pre-scale for v_sin/v_cos
constexpr float C8  = 4.1168160e-7f;   // (2*pi)^-8
constexpr float EPS = 1e-4f;

// ws layout (bytes):
//   qkv f32:  [0, 4718592)         3 * (2*12*256*64) * 4
//   A' bf16:  [4718592, 6291456)   512 x 1536  (xh | xl)
//   B' bf16:  [6291456, 13369344)  2304 x 1536 (Wh | Wl)
//   QT  f32:  [13369344, 18087936) [bh][row][3][64]  (q*R2, sin, cos)
//   KT  f32:  [18087936, 22806528) [bh][dim][3][256] key-coalesced
#define QKV_ELEMS (NB*NH*SS*WW)
#define A_OFF_BYTES  4718592u
#define B_OFF_BYTES  6291456u
#define QT_OFF_BYTES 13369344u
#define KT_OFF_BYTES 18087936u

#define XBLKS 384    // 512*768/4/256
#define WBLKS 1728   // 3*768*768/4/256

__device__ __forceinline__ unsigned short bf16_rn(float f) {
    unsigned u = __builtin_bit_cast(unsigned, f);
    u += 0x7fffu + ((u >> 16) & 1u);
    return (unsigned short)(u >> 16);
}

// ---------------- merged split conversions: x -> A' [xh|xl], W -> B' [Wh|Wl] ----------------
__global__ __launch_bounds__(256) void conv_all(
        const float* __restrict__ x,
        const float* __restrict__ Wq, const float* __restrict__ Wk, const float* __restrict__ Wv,
        unsigned short* __restrict__ A, unsigned short* __restrict__ B) {
    int bid = blockIdx.x;
    const float* src;
    unsigned short* dstrow;
    if (bid < XBLKS) {
        int idx = bid * 256 + threadIdx.x;
        int m = idx / (DD/4);
        int c = (idx - m*(DD/4)) * 4;
        src = x + (size_t)idx * 4;
        dstrow = A + (size_t)m * 1536 + c;
    } else {
        int idx = (bid - XBLKS) * 256 + threadIdx.x;
        int p = idx / (768*192);
        int rem = idx - p*(768*192);
        const float* W = (p == 0) ? Wq : (p == 1) ? Wk : Wv;
        int j = rem / 192;
        int c = (rem - j*192) * 4;
        src = W + (size_t)rem * 4;
        dstrow = B + (size_t)(p*768 + j) * 1536 + c;
    }
    float4 v = *reinterpret_cast<const float4*>(src);
    float vv[4] = {v.x, v.y, v.z, v.w};
    unsigned short h[4], l[4];
    #pragma unroll
    for (int e = 0; e < 4; ++e) {
        h[e] = bf16_rn(vv[e]);
        float hf = __builtin_bit_cast(float, (unsigned)h[e] << 16);
        l[e] = bf16_rn(vv[e] - hf);
    }
    *reinterpret_cast<ushort4*>(dstrow)       = make_ushort4(h[0], h[1], h[2], h[3]);
    *reinterpret_cast<ushort4*>(dstrow + 768) = make_ushort4(l[0], l[1], l[2], l[3]);
}

// ---------------- split-bf16 MFMA GEMM (R6 structure: 32x32 split-K + prefetch) ----------------
__global__ __launch_bounds__(256, 2) void gemm_qkv(
        const unsigned short* __restrict__ A, const unsigned short* __restrict__ B,
        const float* __restrict__ bq, const float* __restrict__ bk, const float* __restrict__ bv,
        float* __restrict__ qkv) {
    __shared__ float red[4][32*32];
    const int tid = threadIdx.x;
    const int wid = tid >> 6, l = tid & 63;
    const int lr = l & 15, lo_ = l >> 4;
    const int m0 = blockIdx.x * 32, n0 = blockIdx.y * 32;

    const unsigned short* Ap = A + (size_t)(m0 + lr) * 1536 + wid * 192 + lo_ * 8;
    const unsigned short* Bp = B + (size_t)(n0 + lr) * 1536 + wid * 192 + lo_ * 8;

    f32x4 acc00 = 0.f, acc01 = 0.f, acc10 = 0.f, acc11 = 0.f;

    bf16x8 ca0, ca1, cb0, cb1, na0, na1, nb0, nb1;
    ca0 = *reinterpret_cast<const bf16x8*>(Ap);
    ca1 = *reinterpret_cast<const bf16x8*>(Ap + 16*1536);
    cb0 = *reinterpret_cast<const bf16x8*>(Bp);
    cb1 = *reinterpret_cast<const bf16x8*>(Bp + 16*1536);

    #pragma unroll
    for (int it = 0; it < 18; ++it) {
        if (it < 17) {
            const int it1 = it + 1;
            const int seg1 = it1 / 6, kk1 = it1 - seg1 * 6;
            const int ao = ((seg1 == 2) ? 768 : 0) + kk1 * 32;
            const int bo = ((seg1 == 1) ? 768 : 0) + kk1 * 32;
            na0 = *reinterpret_cast<const bf16x8*>(Ap + ao);
            na1 = *reinterpret_cast<const bf16x8*>(Ap + 16*1536 + ao);
            nb0 = *reinterpret_cast<const bf16x8*>(Bp + bo);
            nb1 = *reinterpret_cast<const bf16x8*>(Bp + 16*1536 + bo);
        }
        acc00 = __builtin_amdgcn_mfma_f32_16x16x32_bf16(ca0, cb0, acc00, 0, 0, 0);
        acc01 = __builtin_amdgcn_mfma_f32_16x16x32_bf16(ca0, cb1, acc01, 0, 0, 0);
        acc10 = __builtin_amdgcn_mfma_f32_16x16x32_bf16(ca1, cb0, acc10, 0, 0, 0);
        acc11 = __builtin_amdgcn_mfma_f32_16x16x32_bf16(ca1, cb1, acc11, 0, 0, 0);
        ca0 = na0; ca1 = na1; cb0 = nb0; cb1 = nb1;
    }

    #pragma unroll
    for (int j = 0; j < 4; ++j) {
        int r0 = lo_ * 4 + j;
        red[wid][(r0     ) * 32 + lr     ] = acc00[j];
        red[wid][(r0     ) * 32 + lr + 16] = acc01[j];
        red[wid][(r0 + 16) * 32 + lr     ] = acc10[j];
        red[wid][(r0 + 16) * 32 + lr + 16] = acc11[j];
    }
    __syncthreads();

    int row = tid >> 3, col = (tid & 7) * 4;
    f32x4 s = *reinterpret_cast<f32x4*>(&red[0][row*32 + col]);
    #pragma unroll
    for (int w = 1; w < 4; ++w)
        s += *reinterpret_cast<f32x4*>(&red[w][row*32 + col]);

    int n = n0 + col;
    int which = n / 768;
    int jj = n - which * 768;
    const float* bias = (which == 0) ? bq : (which == 1) ? bk : bv;
    float4 bb = *reinterpret_cast<const float4*>(&bias[jj]);
    s[0] += bb.x; s[1] += bb.y; s[2] += bb.z; s[3] += bb.w;

    int m = m0 + row, b_ = m >> 8, s_ = m & 255;
    int head = jj >> 6, w = jj & 63;
    float* o = qkv + (size_t)which * QKV_ELEMS + (((size_t)b_ * NH + head) * SS + s_) * WW + w;
    *reinterpret_cast<float4*>(o) = make_float4(s[0], s[1], s[2], s[3]);
}

// ---------------- prep: q,k -> (val*R2, sin, cos) triples ----------------
__global__ __launch_bounds__(256) void prep(const float* __restrict__ qkv,
                                            float* __restrict__ QT, float* __restrict__ KT) {
    const int c = blockIdx.x, bh = blockIdx.y;
    const int lane = threadIdx.x & 63, wv = threadIdx.x >> 6;
    const int key = c * 64 + lane;
    const int d0 = wv * 16;
    const float* q = qkv + ((size_t)bh * SS + key) * WW + d0;
    const float* k = qkv + QKV_ELEMS + ((size_t)bh * SS + key) * WW + d0;
    float* qt = QT + ((size_t)bh * SS + key) * 3 * WW;     // [key][3][64]
    float* kt = KT + (size_t)bh * WW * 3 * SS;             // [d][3][256]
    #pragma unroll
    for (int g = 0; g < 4; ++g) {
        float4 qv = *reinterpret_cast<const float4*>(q + g * 4);
        float4 kv = *reinterpret_cast<const float4*>(k + g * 4);
        float qa[4] = {qv.x, qv.y, qv.z, qv.w};
        float ka[4] = {kv.x, kv.y, kv.z, kv.w};
        f32x4 qr, qs, qc;
        #pragma unroll
        for (int e = 0; e < 4; ++e) {
            float a = R2 * qa[e];
            qr[e] = a;
            qs[e] = __builtin_amdgcn_sinf(a);
            qc[e] = __builtin_amdgcn_cosf(a);
        }
        *reinterpret_cast<f32x4*>(qt + 0 * WW + d0 + g * 4) = qr;
        *reinterpret_cast<f32x4*>(qt + 1 * WW + d0 + g * 4) = qs;
        *reinterpret_cast<f32x4*>(qt + 2 * WW + d0 + g * 4) = qc;
        #pragma unroll
        for (int e = 0; e < 4; ++e) {
            float a = R2 * ka[e];
            int d = d0 + g * 4 + e;
            kt[(d * 3 + 0) * SS + key] = a;
            kt[(d * 3 + 1) * SS + key] = __builtin_amdgcn_sinf(a);
            kt[(d * 3 + 2) * SS + key] = __builtin_amdgcn_cosf(a);
        }
    }
}

// ---------------- Fourier attention v7: v5 core + wave-uniform early-out ----------------
// thread = key. Score via angle-difference identity (0 trans in loop).
// |pg| is non-increasing (|sinc|<=1; guarded dims contribute exactly 1), so after
// 3 groups (24 dims), if all lanes have |pg| <= 2^-7 the final exp() is bit-identical
// to the full product (pg^4 <= 2^-28 -> expf rounds to the same float) -> skip groups 3..7.
__global__ __launch_bounds__(256, 3) void fattn(
    const float* __restrict__ qkv, const float* __restrict__ QT, const float* __restrict__ KT,
    const float* __restrict__ mask, float* __restrict__ out)
{
    const int bh = blockIdx.y;
    const int b = bh / NH, h = bh - b * NH;
    const int row0 = blockIdx.x * 8;

    const float* Vg = qkv + (size_t)(2 * QKV_ELEMS) + (size_t)bh * SS * WW;
    const float* kt = KT + (size_t)bh * WW * 3 * SS;

    __shared__ __align__(16) float qt[8][3][WW];     // 6 KB: per-row (q, sin, cos)
    __shared__ __align__(16) float ebuf[SS][8];      // 8 KB
    __shared__ __align__(16) float ypart[4][8][WW];  // 8 KB
    __shared__ float zs[4][8];

    const int tid = threadIdx.x, lane = tid & 63, wid = tid >> 6;

    // stage q triples (1536 contiguous floats)
    {
        const f32x4* qsrc = reinterpret_cast<const f32x4*>(QT + ((size_t)bh * SS + row0) * 3 * WW);
        f32x4* qdst = reinterpret_cast<f32x4*>(&qt[0][0][0]);
        qdst[tid] = qsrc[tid];
        if (tid < 128) qdst[tid + 256] = qsrc[tid + 256];
    }
    const float mt = -10000.0f * (1.0f - mask[b * SS + tid]);
    __syncthreads();

    float pg[8] = {1.f,1.f,1.f,1.f,1.f,1.f,1.f,1.f};

    auto score_group = [&](int g) {
        const float* kg = kt + (size_t)g * 8 * 3 * SS + tid;
        float kk[8], sk[8], ck[8];
        #pragma unroll
        for (int j = 0; j < 8; ++j) {
            kk[j] = kg[j * 3 * SS];
            sk[j] = kg[j * 3 * SS + SS];
            ck[j] = kg[j * 3 * SS + 2 * SS];
        }
        #pragma unroll
        for (int r = 0; r < 8; ++r) {
            f32x4 q0 = *reinterpret_cast<const f32x4*>(&qt[r][0][g*8]);
            f32x4 q1 = *reinterpret_cast<const f32x4*>(&qt[r][0][g*8+4]);
            f32x4 s0 = *reinterpret_cast<const f32x4*>(&qt[r][1][g*8]);
            f32x4 s1 = *reinterpret_cast<const f32x4*>(&qt[r][1][g*8+4]);
            f32x4 c0 = *reinterpret_cast<const f32x4*>(&qt[r][2][g*8]);
            f32x4 c1 = *reinterpret_cast<const f32x4*>(&qt[r][2][g*8+4]);
            float ps = 1.f, pt = 1.f;
            #pragma unroll
            for (int j = 0; j < 8; ++j) {
                float qv = (j < 4) ? q0[j] : q1[j-4];
                float sq = (j < 4) ? s0[j] : s1[j-4];
                float cq = (j < 4) ? c0[j] : c1[j-4];
                float t  = qv - kk[j];
                float at = fmaxf(fabsf(t), EPS);
                float sn = fmaf(sq, ck[j], -(cq * sk[j]));   // sin(q^ - k^)
                sn = (fabsf(t) < EPS) ? at : sn;             // factor -> exactly 1 near t=0
                ps *= sn;
                pt *= at;
            }
            pg[r] *= (ps * C8) * __builtin_amdgcn_rcpf(pt);
        }
    };

    // phase 1: groups 0..2 (24 dims)
    for (int g = 0; g < 3; ++g) score_group(g);

    // wave-uniform early-out: if every lane's |pg| <= 2^-7, remaining groups
    // cannot change any rounded exp() result.
    float mx = fabsf(pg[0]);
    #pragma unroll
    for (int r = 1; r < 8; ++r) mx = fmaxf(mx, fabsf(pg[r]));
    if (__any(mx > 0.0078125f)) {
        for (int g = 3; g < 8; ++g) score_group(g);
    }

    // e = exp(score + maskterm), score = pg^4; stash + per-wave Z
    float e[8];
    #pragma unroll
    for (int r = 0; r < 8; ++r) {
        float p = pg[r];
        p *= p; p *= p;
        e[r] = __expf(p + mt);
    }
    {
        f32x4 e0, e1;
        #pragma unroll
        for (int r = 0; r < 4; ++r) { e0[r] = e[r]; e1[r] = e[r+4]; }
        *reinterpret_cast<f32x4*>(&ebuf[tid][0]) = e0;   // wave-local
        *reinterpret_cast<f32x4*>(&ebuf[tid][4]) = e1;
    }
    #pragma unroll
    for (int r = 0; r < 8; ++r) {
        float z = e[r];
        #pragma unroll
        for (int off = 32; off; off >>= 1) z += __shfl_xor(z, off);
        if (lane == 0) zs[wid][r] = z;
    }

    // PV: lane = output dim w; wave covers its own 64 keys
    float y[8] = {0.f,0.f,0.f,0.f,0.f,0.f,0.f,0.f};
    const float* vb = Vg + (size_t)(wid * 64) * WW + lane;
    #pragma unroll 16
    for (int ii = 0; ii < 64; ++ii) {
        float v = vb[ii * WW];
        f32x4 ea = *reinterpret_cast<const f32x4*>(&ebuf[wid*64 + ii][0]);
        f32x4 eb = *reinterpret_cast<const f32x4*>(&ebuf[wid*64 + ii][4]);
        y[0] = fmaf(ea[0], v, y[0]); y[1] = fmaf(ea[1], v, y[1]);
        y[2] = fmaf(ea[2], v, y[2]); y[3] = fmaf(ea[3], v, y[3]);
        y[4] = fmaf(eb[0], v, y[4]); y[5] = fmaf(eb[1], v, y[5]);
        y[6] = fmaf(eb[2], v, y[6]); y[7] = fmaf(eb[3], v, y[7]);
    }
    #pragma unroll
    for (int r = 0; r < 8; ++r) ypart[wid][r][lane] = y[r];
    __syncthreads();

    {
        const int r0 = tid >> 6;
        #pragma unroll
        for (int q = 0; q < 2; ++q) {
            int rr = r0 + q * 4;
            float yy = ypart[0][rr][lane] + ypart[1][rr][lane]
                     + ypart[2][rr][lane] + ypart[3][rr][lane];
            float zz = zs[0][rr] + zs[1][rr] + zs[2][rr] + zs[3][rr];
            out[((size_t)b * SS + row0 + rr) * DD + h * WW + lane] = yy * __builtin_amdgcn_rcpf(zz);
        }
    }
}

extern "C" void kernel_launch(void* const* d_in, const int* in_sizes, int n_in,
                              void* d_out, int out_size, void* d_ws, size_t ws_size,
                              hipStream_t stream) {
    const float* x    = (const float*)d_in[0];
    const float* mask = (const float*)d_in[1];
    const float* Wq   = (const float*)d_in[2];
    const float* bq   = (const float*)d_in[3];
    const float* Wk   = (const float*)d_in[4];
    const float* bk   = (const float*)d_in[5];
    const float* Wv   = (const float*)d_in[6];
    const float* bv   = (const float*)d_in[7];
    float* out = (float*)d_out;

    float*          qkv = (float*)d_ws;
    unsigned short* Ab  = (unsigned short*)((char*)d_ws + A_OFF_BYTES);
    unsigned short* Bb  = (unsigned short*)((char*)d_ws + B_OFF_BYTES);
    float*          QTp = (float*)((char*)d_ws + QT_OFF_BYTES);
    float*          KTp = (float*)((char*)d_ws + KT_OFF_BYTES);

    conv_all<<<dim3(XBLKS + WBLKS), 256, 0, stream>>>(x, Wq, Wk, Wv, Ab, Bb);
    gemm_qkv<<<dim3(512/32, 2304/32), 256, 0, stream>>>(Ab, Bb, bq, bk, bv, qkv);
    prep<<<dim3(4, NB*NH), 256, 0, stream>>>(qkv, QTp, KTp);
    fattn<<<dim3(SS/8, NB*NH), 256, 0, stream>>>(qkv, QTp, KTp, mask, out);
}

// Round 9
// 58.782 us; speedup vs baseline: 1.5862x; 1.1767x over previous
//
#include <hip/hip_runtime.h>
#include <math.h>

#define NB 2
#define SS 256
#define DD 768
#define NH 12
#define WW 64

using f32x4  = __attribute__((ext_vector_type(4))) float;
using bf16x8 = __attribute__((ext_vector_type(8))) short;

constexpr float R2  = 0.25f;           // R/2: revolutions pre-scale for v_sin/v_cos
constexpr float C8  = 4.1168160e-7f;   // (2*pi)^-8
constexpr float EPS = 1e-4f;
constexpr float THR = 0.0078125f;      // 2^-7: |pg|<=THR -> pg^4<=2^-28 -> expf bit-identical

// ws layout (bytes):
//   qkv f32:  [0, 4718592)         only V region [2*QKV_ELEMS..) is used now
//   A' bf16:  [4718592, 6291456)   512 x 1536  (xh | xl)
//   B' bf16:  [6291456, 13369344)  2304 x 1536 (Wh | Wl)
//   QT  f32:  [13369344, 18087936) [bh][row][3][64]  (q*R2, sin, cos)
//   KT  f32:  [18087936, 22806528) [bh][dim][3][256] key-coalesced
#define QKV_ELEMS (NB*NH*SS*WW)
#define A_OFF_BYTES  4718592u
#define B_OFF_BYTES  6291456u
#define QT_OFF_BYTES 13369344u
#define KT_OFF_BYTES 18087936u

#define XBLKS 384    // 512*768/4/256
#define WBLKS 1728   // 3*768*768/4/256

__device__ __forceinline__ unsigned short bf16_rn(float f) {
    unsigned u = __builtin_bit_cast(unsigned, f);
    u += 0x7fffu + ((u >> 16) & 1u);
    return (unsigned short)(u >> 16);
}

// ---------------- merged split conversions: x -> A' [xh|xl], W -> B' [Wh|Wl] ----------------
__global__ __launch_bounds__(256) void conv_all(
        const float* __restrict__ x,
        const float* __restrict__ Wq, const float* __restrict__ Wk, const float* __restrict__ Wv,
        unsigned short* __restrict__ A, unsigned short* __restrict__ B) {
    int bid = blockIdx.x;
    const float* src;
    unsigned short* dstrow;
    if (bid < XBLKS) {
        int idx = bid * 256 + threadIdx.x;
        int m = idx / (DD/4);
        int c = (idx - m*(DD/4)) * 4;
        src = x + (size_t)idx * 4;
        dstrow = A + (size_t)m * 1536 + c;
    } else {
        int idx = (bid - XBLKS) * 256 + threadIdx.x;
        int p = idx / (768*192);
        int rem = idx - p*(768*192);
        const float* W = (p == 0) ? Wq : (p == 1) ? Wk : Wv;
        int j = rem / 192;
        int c = (rem - j*192) * 4;
        src = W + (size_t)rem * 4;
        dstrow = B + (size_t)(p*768 + j) * 1536 + c;
    }
    float4 v = *reinterpret_cast<const float4*>(src);
    float vv[4] = {v.x, v.y, v.z, v.w};
    unsigned short h[4], l[4];
    #pragma unroll
    for (int e = 0; e < 4; ++e) {
        h[e] = bf16_rn(vv[e]);
        float hf = __builtin_bit_cast(float, (unsigned)h[e] << 16);
        l[e] = bf16_rn(vv[e] - hf);
    }
    *reinterpret_cast<ushort4*>(dstrow)       = make_ushort4(h[0], h[1], h[2], h[3]);
    *reinterpret_cast<ushort4*>(dstrow + 768) = make_ushort4(l[0], l[1], l[2], l[3]);
}

// ---------------- split-bf16 MFMA GEMM + fused prep epilogue ----------------
// 32x32 tile, 4 waves split-K, LDS reduce. q-blocks -> QT triples, k-blocks -> KT
// triples (sin/cos computed here), v-blocks -> qkv V region.
__global__ __launch_bounds__(256, 2) void gemm_qkv(
        const unsigned short* __restrict__ A, const unsigned short* __restrict__ B,
        const float* __restrict__ bq, const float* __restrict__ bk, const float* __restrict__ bv,
        float* __restrict__ qkv, float* __restrict__ QT, float* __restrict__ KT) {
    __shared__ float red[4][32*32];
    const int tid = threadIdx.x;
    const int wid = tid >> 6, l = tid & 63;
    const int lr = l & 15, lo_ = l >> 4;
    const int m0 = blockIdx.x * 32, n0 = blockIdx.y * 32;

    const unsigned short* Ap = A + (size_t)(m0 + lr) * 1536 + wid * 192 + lo_ * 8;
    const unsigned short* Bp = B + (size_t)(n0 + lr) * 1536 + wid * 192 + lo_ * 8;

    f32x4 acc00 = 0.f, acc01 = 0.f, acc10 = 0.f, acc11 = 0.f;

    bf16x8 ca0, ca1, cb0, cb1, na0, na1, nb0, nb1;
    ca0 = *reinterpret_cast<const bf16x8*>(Ap);
    ca1 = *reinterpret_cast<const bf16x8*>(Ap + 16*1536);
    cb0 = *reinterpret_cast<const bf16x8*>(Bp);
    cb1 = *reinterpret_cast<const bf16x8*>(Bp + 16*1536);

    #pragma unroll
    for (int it = 0; it < 18; ++it) {
        if (it < 17) {
            const int it1 = it + 1;
            const int seg1 = it1 / 6, kk1 = it1 - seg1 * 6;
            const int ao = ((seg1 == 2) ? 768 : 0) + kk1 * 32;
            const int bo = ((seg1 == 1) ? 768 : 0) + kk1 * 32;
            na0 = *reinterpret_cast<const bf16x8*>(Ap + ao);
            na1 = *reinterpret_cast<const bf16x8*>(Ap + 16*1536 + ao);
            nb0 = *reinterpret_cast<const bf16x8*>(Bp + bo);
            nb1 = *reinterpret_cast<const bf16x8*>(Bp + 16*1536 + bo);
        }
        acc00 = __builtin_amdgcn_mfma_f32_16x16x32_bf16(ca0, cb0, acc00, 0, 0, 0);
        acc01 = __builtin_amdgcn_mfma_f32_16x16x32_bf16(ca0, cb1, acc01, 0, 0, 0);
        acc10 = __builtin_amdgcn_mfma_f32_16x16x32_bf16(ca1, cb0, acc10, 0, 0, 0);
        acc11 = __builtin_amdgcn_mfma_f32_16x16x32_bf16(ca1, cb1, acc11, 0, 0, 0);
        ca0 = na0; ca1 = na1; cb0 = nb0; cb1 = nb1;
    }

    #pragma unroll
    for (int j = 0; j < 4; ++j) {
        int r0 = lo_ * 4 + j;
        red[wid][(r0     ) * 32 + lr     ] = acc00[j];
        red[wid][(r0     ) * 32 + lr + 16] = acc01[j];
        red[wid][(r0 + 16) * 32 + lr     ] = acc10[j];
        red[wid][(r0 + 16) * 32 + lr + 16] = acc11[j];
    }
    __syncthreads();

    int row = tid >> 3, col = (tid & 7) * 4;
    f32x4 s = *reinterpret_cast<f32x4*>(&red[0][row*32 + col]);
    #pragma unroll
    for (int w = 1; w < 4; ++w)
        s += *reinterpret_cast<f32x4*>(&red[w][row*32 + col]);

    int n = n0 + col;
    int which = n / 768;
    int jj = n - which * 768;
    const float* bias = (which == 0) ? bq : (which == 1) ? bk : bv;
    float4 bb = *reinterpret_cast<const float4*>(&bias[jj]);
    s[0] += bb.x; s[1] += bb.y; s[2] += bb.z; s[3] += bb.w;

    int m = m0 + row, b_ = m >> 8, s_ = m & 255;
    int head = jj >> 6, w = jj & 63;
    int bh = b_ * NH + head;

    if (which == 2) {
        float* o = qkv + (size_t)2 * QKV_ELEMS + ((size_t)bh * SS + s_) * WW + w;
        *reinterpret_cast<float4*>(o) = make_float4(s[0], s[1], s[2], s[3]);
    } else if (which == 0) {
        float* qtb = QT + ((size_t)bh * SS + s_) * 192 + w;
        f32x4 av, sv, cv;
        #pragma unroll
        for (int e = 0; e < 4; ++e) {
            float a = R2 * s[e];
            av[e] = a;
            sv[e] = __builtin_amdgcn_sinf(a);
            cv[e] = __builtin_amdgcn_cosf(a);
        }
        *reinterpret_cast<f32x4*>(qtb)       = av;
        *reinterpret_cast<f32x4*>(qtb + 64)  = sv;
        *reinterpret_cast<f32x4*>(qtb + 128) = cv;
    } else {
        float* ktb = KT + (size_t)bh * WW * 3 * SS;
        #pragma unroll
        for (int e = 0; e < 4; ++e) {
            int d = w + e;
            float a = R2 * s[e];
            ktb[(d*3 + 0) * SS + s_] = a;
            ktb[(d*3 + 1) * SS + s_] = __builtin_amdgcn_sinf(a);
            ktb[(d*3 + 2) * SS + s_] = __builtin_amdgcn_cosf(a);
        }
    }
}

// ---------------- Fourier attention v8: per-row cascading early-out ----------------
// thread = key. Score via angle-difference identity (0 trans in loop).
// |pg| non-increasing; per Q-row r, once __any(|pg[r]|>2^-7) is false the row's
// final expf is bit-identical without the remaining groups -> skip row; break when
// no row is alive. Checks are wave-uniform scalar branches (rows unrolled).
__global__ __launch_bounds__(256, 3) void fattn(
    const float* __restrict__ qkv, const float* __restrict__ QT, const float* __restrict__ KT,
    const float* __restrict__ mask, float* __restrict__ out)
{
    const int bh = blockIdx.y;
    const int b = bh / NH, h = bh - b * NH;
    const int row0 = blockIdx.x * 8;

    const float* Vg = qkv + (size_t)(2 * QKV_ELEMS) + (size_t)bh * SS * WW;
    const float* kt = KT + (size_t)bh * WW * 3 * SS;

    __shared__ __align__(16) float qt[8][3][WW];     // 6 KB
    __shared__ __align__(16) float ebuf[SS][8];      // 8 KB
    __shared__ __align__(16) float ypart[4][8][WW];  // 8 KB
    __shared__ float zs[4][8];

    const int tid = threadIdx.x, lane = tid & 63, wid = tid >> 6;

    // stage q triples (1536 contiguous floats)
    {
        const f32x4* qsrc = reinterpret_cast<const f32x4*>(QT + ((size_t)bh * SS + row0) * 3 * WW);
        f32x4* qdst = reinterpret_cast<f32x4*>(&qt[0][0][0]);
        qdst[tid] = qsrc[tid];
        if (tid < 128) qdst[tid + 256] = qsrc[tid + 256];
    }
    const float mt = -10000.0f * (1.0f - mask[b * SS + tid]);
    __syncthreads();

    float pg[8] = {1.f,1.f,1.f,1.f,1.f,1.f,1.f,1.f};

    auto score_group = [&](int g) {
        const float* kg = kt + (size_t)g * 8 * 3 * SS + tid;
        float kk[8], sk[8], ck[8];
        #pragma unroll
        for (int j = 0; j < 8; ++j) {
            kk[j] = kg[j * 3 * SS];
            sk[j] = kg[j * 3 * SS + SS];
            ck[j] = kg[j * 3 * SS + 2 * SS];
        }
        #pragma unroll
        for (int r = 0; r < 8; ++r) {
            f32x4 q0 = *reinterpret_cast<const f32x4*>(&qt[r][0][g*8]);
            f32x4 q1 = *reinterpret_cast<const f32x4*>(&qt[r][0][g*8+4]);
            f32x4 s0 = *reinterpret_cast<const f32x4*>(&qt[r][1][g*8]);
            f32x4 s1 = *reinterpret_cast<const f32x4*>(&qt[r][1][g*8+4]);
            f32x4 c0 = *reinterpret_cast<const f32x4*>(&qt[r][2][g*8]);
            f32x4 c1 = *reinterpret_cast<const f32x4*>(&qt[r][2][g*8+4]);
            float ps = 1.f, pt = 1.f;
            #pragma unroll
            for (int j = 0; j < 8; ++j) {
                float qv = (j < 4) ? q0[j] : q1[j-4];
                float sq = (j < 4) ? s0[j] : s1[j-4];
                float cq = (j < 4) ? c0[j] : c1[j-4];
                float t  = qv - kk[j];
                float at = fmaxf(fabsf(t), EPS);
                float sn = fmaf(sq, ck[j], -(cq * sk[j]));
                sn = (fabsf(t) < EPS) ? at : sn;
                ps *= sn;
                pt *= at;
            }
            pg[r] *= (ps * C8) * __builtin_amdgcn_rcpf(pt);
        }
    };

    // phase 1: groups 0..2 (24 dims), unconditional
    for (int g = 0; g < 3; ++g) score_group(g);

    // phase 2: per-row cascade over groups 3..7
    bool alive[8];
    bool any8 = false;
    #pragma unroll
    for (int r = 0; r < 8; ++r) {
        alive[r] = __any(fabsf(pg[r]) > THR);
        any8 = any8 || alive[r];
    }
    if (any8) {
        #pragma unroll 1
        for (int g = 3; g < 8; ++g) {
            const float* kg = kt + (size_t)g * 8 * 3 * SS + tid;
            float kk[8], sk[8], ck[8];
            #pragma unroll
            for (int j = 0; j < 8; ++j) {
                kk[j] = kg[j * 3 * SS];
                sk[j] = kg[j * 3 * SS + SS];
                ck[j] = kg[j * 3 * SS + 2 * SS];
            }
            bool still = false;
            #pragma unroll
            for (int r = 0; r < 8; ++r) {
                if (alive[r]) {
                    f32x4 q0 = *reinterpret_cast<const f32x4*>(&qt[r][0][g*8]);
                    f32x4 q1 = *reinterpret_cast<const f32x4*>(&qt[r][0][g*8+4]);
                    f32x4 s0 = *reinterpret_cast<const f32x4*>(&qt[r][1][g*8]);
                    f32x4 s1 = *reinterpret_cast<const f32x4*>(&qt[r][1][g*8+4]);
                    f32x4 c0 = *reinterpret_cast<const f32x4*>(&qt[r][2][g*8]);
                    f32x4 c1 = *reinterpret_cast<const f32x4*>(&qt[r][2][g*8+4]);
                    float ps = 1.f, pt = 1.f;
                    #pragma unroll
                    for (int j = 0; j < 8; ++j) {
                        float qv = (j < 4) ? q0[j] : q1[j-4];
                        float sq = (j < 4) ? s0[j] : s1[j-4];
                        float cq = (j < 4) ? c0[j] : c1[j-4];
                        float t  = qv - kk[j];
                        float at = fmaxf(fabsf(t), EPS);
                        float sn = fmaf(sq, ck[j], -(cq * sk[j]));
                        sn = (fabsf(t) < EPS) ? at : sn;
                        ps *= sn;
                        pt *= at;
                    }
                    pg[r] *= (ps * C8) * __builtin_amdgcn_rcpf(pt);
                    alive[r] = __any(fabsf(pg[r]) > THR);
                }
                still = still || alive[r];
            }
            if (!still) break;
        }
    }

    // e = exp(score + maskterm), score = pg^4; stash + per-wave Z
    float e[8];
    #pragma unroll
    for (int r = 0; r < 8; ++r) {
        float p = pg[r];
        p *= p; p *= p;
        e[r] = __expf(p + mt);
    }
    {
        f32x4 e0, e1;
        #pragma unroll
        for (int r = 0; r < 4; ++r) { e0[r] = e[r]; e1[r] = e[r+4]; }
        *reinterpret_cast<f32x4*>(&ebuf[tid][0]) = e0;   // wave-local
        *reinterpret_cast<f32x4*>(&ebuf[tid][4]) = e1;
    }
    #pragma unroll
    for (int r = 0; r < 8; ++r) {
        float z = e[r];
        #pragma unroll
        for (int off = 32; off; off >>= 1) z += __shfl_xor(z, off);
        if (lane == 0) zs[wid][r] = z;
    }

    // PV: lane = output dim w; wave covers its own 64 keys
    float y[8] = {0.f,0.f,0.f,0.f,0.f,0.f,0.f,0.f};
    const float* vb = Vg + (size_t)(wid * 64) * WW + lane;
    #pragma unroll 16
    for (int ii = 0; ii < 64; ++ii) {
        float v = vb[ii * WW];
        f32x4 ea = *reinterpret_cast<const f32x4*>(&ebuf[wid*64 + ii][0]);
        f32x4 eb = *reinterpret_cast<const f32x4*>(&ebuf[wid*64 + ii][4]);
        y[0] = fmaf(ea[0], v, y[0]); y[1] = fmaf(ea[1], v, y[1]);
        y[2] = fmaf(ea[2], v, y[2]); y[3] = fmaf(ea[3], v, y[3]);
        y[4] = fmaf(eb[0], v, y[4]); y[5] = fmaf(eb[1], v, y[5]);
        y[6] = fmaf(eb[2], v, y[6]); y[7] = fmaf(eb[3], v, y[7]);
    }
    #pragma unroll
    for (int r = 0; r < 8; ++r) ypart[wid][r][lane] = y[r];
    __syncthreads();

    {
        const int r0 = tid >> 6;
        #pragma unroll
        for (int q = 0; q < 2; ++q) {
            int rr = r0 + q * 4;
            float yy = ypart[0][rr][lane] + ypart[1][rr][lane]
                     + ypart[2][rr][lane] + ypart[3][rr][lane];
            float zz = zs[0][rr] + zs[1][rr] + zs[2][rr] + zs[3][rr];
            out[((size_t)b * SS + row0 + rr) * DD + h * WW + lane] = yy * __builtin_amdgcn_rcpf(zz);
        }
    }
}

extern "C" void kernel_launch(void* const* d_in, const int* in_sizes, int n_in,
                              void* d_out, int out_size, void* d_ws, size_t ws_size,
                              hipStream_t stream) {
    const float* x    = (const float*)d_in[0];
    const float* mask = (const float*)d_in[1];
    const float* Wq   = (const float*)d_in[2];
    const float* bq   = (const float*)d_in[3];
    const float* Wk   = (const float*)d_in[4];
    const float* bk   = (const float*)d_in[5];
    const float* Wv   = (const float*)d_in[6];
    const float* bv   = (const float*)d_in[7];
    float* out = (float*)d_out;

    float*          qkv = (float*)d_ws;
    unsigned short* Ab  = (unsigned short*)((char*)d_ws + A_OFF_BYTES);
    unsigned short* Bb  = (unsigned short*)((char*)d_ws + B_OFF_BYTES);
    float*          QTp = (float*)((char*)d_ws + QT_OFF_BYTES);
    float*          KTp = (float*)((char*)d_ws + KT_OFF_BYTES);

    conv_all<<<dim3(XBLKS + WBLKS), 256, 0, stream>>>(x, Wq, Wk, Wv, Ab, Bb);
    gemm_qkv<<<dim3(512/32, 2304/32), 256, 0, stream>>>(Ab, Bb, bq, bk, bv, qkv, QTp, KTp);
    fattn<<<dim3(SS/8, NB*NH), 256, 0, stream>>>(qkv, QTp, KTp, mask, out);
}

// Round 10
// 57.084 us; speedup vs baseline: 1.6334x; 1.0297x over previous
//
#include <hip/hip_runtime.h>
#include <math.h>

#define NB 2
#define SS 256
#define DD 768
#define NH 12
#define WW 64

using f32x2  = __attribute__((ext_vector_type(2))) float;
using f32x4  = __attribute__((ext_vector_type(4))) float;
using bf16x8 = __attribute__((ext_vector_type(8))) short;

constexpr float R2  = 0.25f;           // R/2: revolutions pre-scale for v_sin/v_cos
constexpr float C8  = 4.1168160e-7f;   // (2*pi)^-8
constexpr float EPS = 1e-4f;
constexpr float THR = 0.0078125f;      // 2^-7: |pg|<=THR -> pg^4<=2^-28 -> expf bit-identical

// ws layout (bytes):
//   qkv f32:  [0, 4718592)         only V region [2*QKV_ELEMS..) used
//   A' bf16:  [4718592, 6291456)   512 x 1536  (xh | xl)
//   B' bf16:  [6291456, 13369344)  2304 x 1536 (Wh | Wl)
//   QT  f32:  [13369344, 18087936) [bh][row][3][64]  (q*R2, sin, cos)
//   KT  f32:  [18087936, 22806528) [bh][dim][3][256] key-coalesced
#define QKV_ELEMS (NB*NH*SS*WW)
#define A_OFF_BYTES  4718592u
#define B_OFF_BYTES  6291456u
#define QT_OFF_BYTES 13369344u
#define KT_OFF_BYTES 18087936u

#define XBLKS 384    // 512*768/4/256
#define WBLKS 1728   // 3*768*768/4/256

__device__ __forceinline__ unsigned short bf16_rn(float f) {
    unsigned u = __builtin_bit_cast(unsigned, f);
    u += 0x7fffu + ((u >> 16) & 1u);
    return (unsigned short)(u >> 16);
}

// ---------------- merged split conversions: x -> A' [xh|xl], W -> B' [Wh|Wl] ----------------
__global__ __launch_bounds__(256) void conv_all(
        const float* __restrict__ x,
        const float* __restrict__ Wq, const float* __restrict__ Wk, const float* __restrict__ Wv,
        unsigned short* __restrict__ A, unsigned short* __restrict__ B) {
    int bid = blockIdx.x;
    const float* src;
    unsigned short* dstrow;
    if (bid < XBLKS) {
        int idx = bid * 256 + threadIdx.x;
        int m = idx / (DD/4);
        int c = (idx - m*(DD/4)) * 4;
        src = x + (size_t)idx * 4;
        dstrow = A + (size_t)m * 1536 + c;
    } else {
        int idx = (bid - XBLKS) * 256 + threadIdx.x;
        int p = idx / (768*192);
        int rem = idx - p*(768*192);
        const float* W = (p == 0) ? Wq : (p == 1) ? Wk : Wv;
        int j = rem / 192;
        int c = (rem - j*192) * 4;
        src = W + (size_t)rem * 4;
        dstrow = B + (size_t)(p*768 + j) * 1536 + c;
    }
    float4 v = *reinterpret_cast<const float4*>(src);
    float vv[4] = {v.x, v.y, v.z, v.w};
    unsigned short h[4], l[4];
    #pragma unroll
    for (int e = 0; e < 4; ++e) {
        h[e] = bf16_rn(vv[e]);
        float hf = __builtin_bit_cast(float, (unsigned)h[e] << 16);
        l[e] = bf16_rn(vv[e] - hf);
    }
    *reinterpret_cast<ushort4*>(dstrow)       = make_ushort4(h[0], h[1], h[2], h[3]);
    *reinterpret_cast<ushort4*>(dstrow + 768) = make_ushort4(l[0], l[1], l[2], l[3]);
}

// ---------------- split-bf16 MFMA GEMM + fused prep epilogue; 2-deep prefetch ----------------
__global__ __launch_bounds__(256, 2) void gemm_qkv(
        const unsigned short* __restrict__ A, const unsigned short* __restrict__ B,
        const float* __restrict__ bq, const float* __restrict__ bk, const float* __restrict__ bv,
        float* __restrict__ qkv, float* __restrict__ QT, float* __restrict__ KT) {
    __shared__ float red[4][32*32];
    const int tid = threadIdx.x;
    const int wid = tid >> 6, l = tid & 63;
    const int lr = l & 15, lo_ = l >> 4;
    const int m0 = blockIdx.x * 32, n0 = blockIdx.y * 32;

    const unsigned short* Ap = A + (size_t)(m0 + lr) * 1536 + wid * 192 + lo_ * 8;
    const unsigned short* Bp = B + (size_t)(n0 + lr) * 1536 + wid * 192 + lo_ * 8;

    f32x4 acc00 = 0.f, acc01 = 0.f, acc10 = 0.f, acc11 = 0.f;

    // 3-buffer, 2-step-ahead register prefetch; all indices compile-time (full unroll)
    bf16x8 a0[3], a1[3], b0[3], b1[3];
    #define LDSTEP(s, bi) { \
        const int seg_ = (s)/6, kq_ = (s) - seg_*6; \
        const int ao_ = ((seg_ == 2) ? 768 : 0) + kq_*32; \
        const int bo_ = ((seg_ == 1) ? 768 : 0) + kq_*32; \
        a0[bi] = *reinterpret_cast<const bf16x8*>(Ap + ao_); \
        a1[bi] = *reinterpret_cast<const bf16x8*>(Ap + 16*1536 + ao_); \
        b0[bi] = *reinterpret_cast<const bf16x8*>(Bp + bo_); \
        b1[bi] = *reinterpret_cast<const bf16x8*>(Bp + 16*1536 + bo_); }

    LDSTEP(0, 0)
    LDSTEP(1, 1)
    #pragma unroll
    for (int it = 0; it < 18; ++it) {
        if (it + 2 < 18) { LDSTEP(it + 2, (it + 2) % 3) }
        const int cb = it % 3;
        acc00 = __builtin_amdgcn_mfma_f32_16x16x32_bf16(a0[cb], b0[cb], acc00, 0, 0, 0);
        acc01 = __builtin_amdgcn_mfma_f32_16x16x32_bf16(a0[cb], b1[cb], acc01, 0, 0, 0);
        acc10 = __builtin_amdgcn_mfma_f32_16x16x32_bf16(a1[cb], b0[cb], acc10, 0, 0, 0);
        acc11 = __builtin_amdgcn_mfma_f32_16x16x32_bf16(a1[cb], b1[cb], acc11, 0, 0, 0);
    }
    #undef LDSTEP

    #pragma unroll
    for (int j = 0; j < 4; ++j) {
        int r0 = lo_ * 4 + j;
        red[wid][(r0     ) * 32 + lr     ] = acc00[j];
        red[wid][(r0     ) * 32 + lr + 16] = acc01[j];
        red[wid][(r0 + 16) * 32 + lr     ] = acc10[j];
        red[wid][(r0 + 16) * 32 + lr + 16] = acc11[j];
    }
    __syncthreads();

    int row = tid >> 3, col = (tid & 7) * 4;
    f32x4 s = *reinterpret_cast<f32x4*>(&red[0][row*32 + col]);
    #pragma unroll
    for (int w = 1; w < 4; ++w)
        s += *reinterpret_cast<f32x4*>(&red[w][row*32 + col]);

    int n = n0 + col;
    int which = n / 768;
    int jj = n - which * 768;
    const float* bias = (which == 0) ? bq : (which == 1) ? bk : bv;
    float4 bb = *reinterpret_cast<const float4*>(&bias[jj]);
    s[0] += bb.x; s[1] += bb.y; s[2] += bb.z; s[3] += bb.w;

    int m = m0 + row, b_ = m >> 8, s_ = m & 255;
    int head = jj >> 6, w = jj & 63;
    int bh = b_ * NH + head;

    if (which == 2) {
        float* o = qkv + (size_t)2 * QKV_ELEMS + ((size_t)bh * SS + s_) * WW + w;
        *reinterpret_cast<float4*>(o) = make_float4(s[0], s[1], s[2], s[3]);
    } else if (which == 0) {
        float* qtb = QT + ((size_t)bh * SS + s_) * 192 + w;
        f32x4 av, sv, cv;
        #pragma unroll
        for (int e = 0; e < 4; ++e) {
            float a = R2 * s[e];
            av[e] = a;
            sv[e] = __builtin_amdgcn_sinf(a);
            cv[e] = __builtin_amdgcn_cosf(a);
        }
        *reinterpret_cast<f32x4*>(qtb)       = av;
        *reinterpret_cast<f32x4*>(qtb + 64)  = sv;
        *reinterpret_cast<f32x4*>(qtb + 128) = cv;
    } else {
        float* ktb = KT + (size_t)bh * WW * 3 * SS;
        #pragma unroll
        for (int e = 0; e < 4; ++e) {
            int d = w + e;
            float a = R2 * s[e];
            ktb[(d*3 + 0) * SS + s_] = a;
            ktb[(d*3 + 1) * SS + s_] = __builtin_amdgcn_sinf(a);
            ktb[(d*3 + 2) * SS + s_] = __builtin_amdgcn_cosf(a);
        }
    }
}

// ---------------- Fourier attention v9: scalar-pipe q, LDS-free score, packed PV ----------------
// thread = key. q/sin/cos triples are block-uniform -> uniform global loads (s_load into
// SGPRs, scalar pipe), so the score loop touches NO LDS; k triples per-lane VMEM; math VALU.
// Per-row cascading early-out as v8. PV uses v_pk_fma over row pairs; ebuf/ypart keep LDS.
__global__ __launch_bounds__(256, 3) void fattn(
    const float* __restrict__ qkv, const float* __restrict__ QT, const float* __restrict__ KT,
    const float* __restrict__ mask, float* __restrict__ out)
{
    const int bh = blockIdx.y;
    const int b = bh / NH, h = bh - b * NH;
    const int row0 = blockIdx.x * 8;

    const float* Vg = qkv + (size_t)(2 * QKV_ELEMS) + (size_t)bh * SS * WW;
    const float* kt = KT + (size_t)bh * WW * 3 * SS;
    const float* qb = QT + ((size_t)bh * SS + row0) * 192;   // row r: qb + r*192 (+0/64/128)

    __shared__ __align__(16) float ebuf[SS][8];      // 8 KB
    __shared__ __align__(16) float ypart[4][8][WW];  // 8 KB
    __shared__ float zs[4][8];

    const int tid = threadIdx.x, lane = tid & 63, wid = tid >> 6;
    const float mt = -10000.0f * (1.0f - mask[b * SS + tid]);

    float pg[8] = {1.f,1.f,1.f,1.f,1.f,1.f,1.f,1.f};

    auto score_group = [&](int g) {
        const float* kg = kt + (size_t)g * 24 * SS + tid;
        float kk[8], sk[8], ck[8];
        #pragma unroll
        for (int j = 0; j < 8; ++j) {
            kk[j] = kg[j * 3 * SS];
            sk[j] = kg[j * 3 * SS + SS];
            ck[j] = kg[j * 3 * SS + 2 * SS];
        }
        #pragma unroll
        for (int r = 0; r < 8; ++r) {
            const float* qr = qb + r * 192 + g * 8;      // uniform -> s_load
            float4 q0 = *reinterpret_cast<const float4*>(qr);
            float4 q1 = *reinterpret_cast<const float4*>(qr + 4);
            float4 s0 = *reinterpret_cast<const float4*>(qr + 64);
            float4 s1 = *reinterpret_cast<const float4*>(qr + 68);
            float4 c0 = *reinterpret_cast<const float4*>(qr + 128);
            float4 c1 = *reinterpret_cast<const float4*>(qr + 132);
            float qa[8] = {q0.x,q0.y,q0.z,q0.w,q1.x,q1.y,q1.z,q1.w};
            float sa[8] = {s0.x,s0.y,s0.z,s0.w,s1.x,s1.y,s1.z,s1.w};
            float ca[8] = {c0.x,c0.y,c0.z,c0.w,c1.x,c1.y,c1.z,c1.w};
            float ps = 1.f, pt = 1.f;
            #pragma unroll
            for (int j = 0; j < 8; ++j) {
                float t  = qa[j] - kk[j];
                float at = fmaxf(fabsf(t), EPS);
                float sn = fmaf(sa[j], ck[j], -(ca[j] * sk[j]));
                sn = (fabsf(t) < EPS) ? at : sn;
                ps *= sn;
                pt *= at;
            }
            pg[r] *= (ps * C8) * __builtin_amdgcn_rcpf(pt);
        }
    };

    // phase 1: groups 0..2 (24 dims), unconditional
    for (int g = 0; g < 3; ++g) score_group(g);

    // phase 2: per-row cascade over groups 3..7
    bool alive[8];
    bool any8 = false;
    #pragma unroll
    for (int r = 0; r < 8; ++r) {
        alive[r] = __any(fabsf(pg[r]) > THR);
        any8 = any8 || alive[r];
    }
    if (any8) {
        #pragma unroll 1
        for (int g = 3; g < 8; ++g) {
            const float* kg = kt + (size_t)g * 24 * SS + tid;
            float kk[8], sk[8], ck[8];
            #pragma unroll
            for (int j = 0; j < 8; ++j) {
                kk[j] = kg[j * 3 * SS];
                sk[j] = kg[j * 3 * SS + SS];
                ck[j] = kg[j * 3 * SS + 2 * SS];
            }
            bool still = false;
            #pragma unroll
            for (int r = 0; r < 8; ++r) {
                if (alive[r]) {
                    const float* qr = qb + r * 192 + g * 8;
                    float4 q0 = *reinterpret_cast<const float4*>(qr);
                    float4 q1 = *reinterpret_cast<const float4*>(qr + 4);
                    float4 s0 = *reinterpret_cast<const float4*>(qr + 64);
                    float4 s1 = *reinterpret_cast<const float4*>(qr + 68);
                    float4 c0 = *reinterpret_cast<const float4*>(qr + 128);
                    float4 c1 = *reinterpret_cast<const float4*>(qr + 132);
                    float qa[8] = {q0.x,q0.y,q0.z,q0.w,q1.x,q1.y,q1.z,q1.w};
                    float sa[8] = {s0.x,s0.y,s0.z,s0.w,s1.x,s1.y,s1.z,s1.w};
                    float ca[8] = {c0.x,c0.y,c0.z,c0.w,c1.x,c1.y,c1.z,c1.w};
                    float ps = 1.f, pt = 1.f;
                    #pragma unroll
                    for (int j = 0; j < 8; ++j) {
                        float t  = qa[j] - kk[j];
                        float at = fmaxf(fabsf(t), EPS);
                        float sn = fmaf(sa[j], ck[j], -(ca[j] * sk[j]));
                        sn = (fabsf(t) < EPS) ? at : sn;
                        ps *= sn;
                        pt *= at;
                    }
                    pg[r] *= (ps * C8) * __builtin_amdgcn_rcpf(pt);
                    alive[r] = __any(fabsf(pg[r]) > THR);
                }
                still = still || alive[r];
            }
            if (!still) break;
        }
    }

    // e = exp(score + maskterm), score = pg^4; stash + per-wave Z
    float e[8];
    #pragma unroll
    for (int r = 0; r < 8; ++r) {
        float p = pg[r];
        p *= p; p *= p;
        e[r] = __expf(p + mt);
    }
    {
        f32x4 e0, e1;
        #pragma unroll
        for (int r = 0; r < 4; ++r) { e0[r] = e[r]; e1[r] = e[r+4]; }
        *reinterpret_cast<f32x4*>(&ebuf[tid][0]) = e0;   // wave-local
        *reinterpret_cast<f32x4*>(&ebuf[tid][4]) = e1;
    }
    #pragma unroll
    for (int r = 0; r < 8; ++r) {
        float z = e[r];
        #pragma unroll
        for (int off = 32; off; off >>= 1) z += __shfl_xor(z, off);
        if (lane == 0) zs[wid][r] = z;
    }

    // PV: lane = output dim w; wave covers its own 64 keys; row-pair packed FMA
    f32x2 y01 = {0.f,0.f}, y23 = {0.f,0.f}, y45 = {0.f,0.f}, y67 = {0.f,0.f};
    const float* vb = Vg + (size_t)(wid * 64) * WW + lane;
    #pragma unroll 16
    for (int ii = 0; ii < 64; ++ii) {
        float v = vb[ii * WW];
        f32x2 vv; vv[0] = v; vv[1] = v;
        f32x4 ea = *reinterpret_cast<const f32x4*>(&ebuf[wid*64 + ii][0]);
        f32x4 eb = *reinterpret_cast<const f32x4*>(&ebuf[wid*64 + ii][4]);
        f32x2 e01; e01[0] = ea[0]; e01[1] = ea[1];
        f32x2 e23; e23[0] = ea[2]; e23[1] = ea[3];
        f32x2 e45; e45[0] = eb[0]; e45[1] = eb[1];
        f32x2 e67; e67[0] = eb[2]; e67[1] = eb[3];
        y01 += e01 * vv;   // v_pk_fma_f32
        y23 += e23 * vv;
        y45 += e45 * vv;
        y67 += e67 * vv;
    }
    ypart[wid][0][lane] = y01[0]; ypart[wid][1][lane] = y01[1];
    ypart[wid][2][lane] = y23[0]; ypart[wid][3][lane] = y23[1];
    ypart[wid][4][lane] = y45[0]; ypart[wid][5][lane] = y45[1];
    ypart[wid][6][lane] = y67[0]; ypart[wid][7][lane] = y67[1];
    __syncthreads();

    {
        const int r0 = tid >> 6;
        #pragma unroll
        for (int q = 0; q < 2; ++q) {
            int rr = r0 + q * 4;
            float yy = ypart[0][rr][lane] + ypart[1][rr][lane]
                     + ypart[2][rr][lane] + ypart[3][rr][lane];
            float zz = zs[0][rr] + zs[1][rr] + zs[2][rr] + zs[3][rr];
            out[((size_t)b * SS + row0 + rr) * DD + h * WW + lane] = yy * __builtin_amdgcn_rcpf(zz);
        }
    }
}

extern "C" void kernel_launch(void* const* d_in, const int* in_sizes, int n_in,
                              void* d_out, int out_size, void* d_ws, size_t ws_size,
                              hipStream_t stream) {
    const float* x    = (const float*)d_in[0];
    const float* mask = (const float*)d_in[1];
    const float* Wq   = (const float*)d_in[2];
    const float* bq   = (const float*)d_in[3];
    const float* Wk   = (const float*)d_in[4];
    const float* bk   = (const float*)d_in[5];
    const float* Wv   = (const float*)d_in[6];
    const float* bv   = (const float*)d_in[7];
    float* out = (float*)d_out;

    float*          qkv = (float*)d_ws;
    unsigned short* Ab  = (unsigned short*)((char*)d_ws + A_OFF_BYTES);
    unsigned short* Bb  = (unsigned short*)((char*)d_ws + B_OFF_BYTES);
    float*          QTp = (float*)((char*)d_ws + QT_OFF_BYTES);
    float*          KTp = (float*)((char*)d_ws + KT_OFF_BYTES);

    conv_all<<<dim3(XBLKS + WBLKS), 256, 0, stream>>>(x, Wq, Wk, Wv, Ab, Bb);
    gemm_qkv<<<dim3(512/32, 2304/32), 256, 0, stream>>>(Ab, Bb, bq, bk, bv, qkv, QTp, KTp);
    fattn<<<dim3(SS/8, NB*NH), 256, 0, stream>>>(qkv, QTp, KTp, mask, out);
}